// Round 1
// baseline (1029.071 us; speedup 1.0000x reference)
//
#include <hip/hip_runtime.h>
#include <math.h>

#define N_NODES 100000
#define N_EDGES 1600000
#define DIN 128
#define DH 32
#define NEG_SLOPE 0.2f
#define BN_EPS 1e-5f

// ---------------- CSR build ----------------

__global__ void hist_kernel(const int* __restrict__ dst, int* __restrict__ deg, int e) {
    int i = blockIdx.x * blockDim.x + threadIdx.x;
    if (i < e) atomicAdd(&deg[dst[i]], 1);
}

__global__ void scan_kernel(const int* __restrict__ deg, int* __restrict__ off, int n) {
    __shared__ int part[1024];
    int t = threadIdx.x;
    int chunk = (n + 1023) >> 10;
    int lo = t * chunk, hi = min(lo + chunk, n);
    int s = 0;
    for (int i = lo; i < hi; ++i) s += deg[i];
    part[t] = s;
    __syncthreads();
    for (int d = 1; d < 1024; d <<= 1) {
        int v = (t >= d) ? part[t - d] : 0;
        __syncthreads();
        part[t] += v;
        __syncthreads();
    }
    int run = (t == 0) ? 0 : part[t - 1];
    for (int i = lo; i < hi; ++i) { off[i] = run; run += deg[i]; }
    if (t == 1023) off[n] = part[1023];
}

__global__ void scatter_kernel(const int* __restrict__ src, const int* __restrict__ dst,
                               const int* __restrict__ et, const int* __restrict__ off,
                               int* __restrict__ cursor, int* __restrict__ packed, int e) {
    int i = blockIdx.x * blockDim.x + threadIdx.x;
    if (i < e) {
        int d = dst[i];
        int pos = off[d] + atomicAdd(&cursor[d], 1);
        packed[pos] = src[i] | (et[i] << 30);
    }
}

// ---------------- node transforms ----------------
// One 32-lane half-wave per (node, relation); lane = output feature.

__global__ __launch_bounds__(256) void transform0_kernel(
    const float* __restrict__ x, const float* __restrict__ W,
    const float* __restrict__ Qw, const float* __restrict__ Kw,
    float* __restrict__ y, float* __restrict__ qv, float* __restrict__ kv, int n) {
    int g = (blockIdx.x * blockDim.x + threadIdx.x) >> 5;
    int lane = threadIdx.x & 31;
    if (g >= n * 2) return;
    int node = g >> 1, r = g & 1;
    const float4* x4 = (const float4*)(x + (size_t)node * DIN);
    const float* Wr = W + (size_t)r * DIN * DH + lane;
    float acc = 0.f;
#pragma unroll 8
    for (int d4 = 0; d4 < DIN / 4; ++d4) {
        float4 xv = x4[d4];
        acc += xv.x * Wr[(d4 * 4 + 0) * DH];
        acc += xv.y * Wr[(d4 * 4 + 1) * DH];
        acc += xv.z * Wr[(d4 * 4 + 2) * DH];
        acc += xv.w * Wr[(d4 * 4 + 3) * DH];
    }
    y[(size_t)g * DH + lane] = acc;
    float q = acc * Qw[r * DH + lane];
    float k = acc * Kw[r * DH + lane];
    for (int d = 16; d > 0; d >>= 1) {
        q += __shfl_xor(q, d, 32);
        k += __shfl_xor(k, d, 32);
    }
    if (lane == 0) { qv[g] = q; kv[g] = k; }
}

// hidden-layer transform with previous layer's BatchNorm fused in
__global__ __launch_bounds__(256) void transform_h_kernel(
    const float* __restrict__ hpre, const float* __restrict__ stats,
    const float* __restrict__ gamma, const float* __restrict__ beta,
    const float* __restrict__ W, const float* __restrict__ Qw, const float* __restrict__ Kw,
    float* __restrict__ y, float* __restrict__ qv, float* __restrict__ kv, int n) {
    int g = (blockIdx.x * blockDim.x + threadIdx.x) >> 5;
    int lane = threadIdx.x & 31;
    if (g >= n * 2) return;
    int node = g >> 1, r = g & 1;
    float mu = stats[lane] * (1.f / N_NODES);
    float var = stats[DH + lane] * (1.f / N_NODES) - mu * mu;
    float inv = rsqrtf(var + BN_EPS);
    float h = gamma[lane] * (hpre[(size_t)node * DH + lane] - mu) * inv + beta[lane];
    const float* Wr = W + (size_t)r * DH * DH + lane;
    float acc = 0.f;
#pragma unroll
    for (int d = 0; d < DH; ++d) {
        float hd = __shfl(h, d, 32);
        acc += hd * Wr[d * DH];
    }
    y[(size_t)g * DH + lane] = acc;
    float q = acc * Qw[r * DH + lane];
    float k = acc * Kw[r * DH + lane];
    for (int d = 16; d > 0; d >>= 1) {
        q += __shfl_xor(q, d, 32);
        k += __shfl_xor(k, d, 32);
    }
    if (lane == 0) { qv[g] = q; kv[g] = k; }
}

// ---------------- fused attention + aggregate + relu + BN stats ----------------
// One 32-lane half-wave per destination node. Deterministic per-node sums (no
// float atomics on the output).

__global__ __launch_bounds__(256) void attn_kernel(
    const int* __restrict__ off, const int* __restrict__ packed,
    const float* __restrict__ y, const float* __restrict__ qv, const float* __restrict__ kv,
    const float* __restrict__ bias, float* __restrict__ hpre,
    float* __restrict__ stats, int n) {
    __shared__ float ssum[DH], ssq[DH];
    if (threadIdx.x < DH) { ssum[threadIdx.x] = 0.f; ssq[threadIdx.x] = 0.f; }
    __syncthreads();
    int lane = threadIdx.x & 31;
    int sub = threadIdx.x >> 5;
    int subs_per_block = blockDim.x >> 5;
    float rsum = 0.f, rsq = 0.f;
    for (int node = blockIdx.x * subs_per_block + sub; node < n;
         node += gridDim.x * subs_per_block) {
        int lo = off[node], hi = off[node + 1];
        float q0 = qv[node * 2], q1 = qv[node * 2 + 1];
        // pass 1: segment max
        float m = -3.402823e38f;
        for (int i = lo + lane; i < hi; i += 32) {
            int p = packed[i];
            int s = p & 0x3FFFFFFF, r = p >> 30;
            float e = (r ? q1 : q0) + kv[s * 2 + r];
            e = e > 0.f ? e : NEG_SLOPE * e;
            m = fmaxf(m, e);
        }
        for (int d = 16; d > 0; d >>= 1) m = fmaxf(m, __shfl_xor(m, d, 32));
        // pass 2: sum of exp
        float sum = 0.f;
        for (int i = lo + lane; i < hi; i += 32) {
            int p = packed[i];
            int s = p & 0x3FFFFFFF, r = p >> 30;
            float e = (r ? q1 : q0) + kv[s * 2 + r];
            e = e > 0.f ? e : NEG_SLOPE * e;
            sum += __expf(e - m);
        }
        for (int d = 16; d > 0; d >>= 1) sum += __shfl_xor(sum, d, 32);
        float inv = 1.f / (sum + 1e-16f);
        // pass 3: weighted aggregation; lane = feature
        float acc = 0.f;
        for (int i = lo; i < hi; ++i) {
            int p = packed[i];
            int s = p & 0x3FFFFFFF, r = p >> 30;
            float e = (r ? q1 : q0) + kv[s * 2 + r];
            e = e > 0.f ? e : NEG_SLOPE * e;
            float alpha = __expf(e - m) * inv;
            acc += alpha * y[(size_t)(s * 2 + r) * DH + lane];
        }
        float h = fmaxf(acc + bias[lane], 0.f);
        hpre[(size_t)node * DH + lane] = h;
        rsum += h;
        rsq += h * h;
    }
    atomicAdd(&ssum[lane], rsum);
    atomicAdd(&ssq[lane], rsq);
    __syncthreads();
    if (threadIdx.x < DH) {
        atomicAdd(&stats[threadIdx.x], ssum[threadIdx.x]);
        atomicAdd(&stats[DH + threadIdx.x], ssq[threadIdx.x]);
    }
}

// ---------------- final BN + MLP head ----------------

__global__ __launch_bounds__(256) void mlp_kernel(
    const float* __restrict__ hpre, const float* __restrict__ stats,
    const float* __restrict__ gamma, const float* __restrict__ beta,
    const float* __restrict__ mw1, const float* __restrict__ mb1,
    const float* __restrict__ mw2, const float* __restrict__ mb2,
    float* __restrict__ out, int n) {
    int g = (blockIdx.x * blockDim.x + threadIdx.x) >> 5;
    int lane = threadIdx.x & 31;
    if (g >= n) return;
    float mu = stats[lane] * (1.f / N_NODES);
    float var = stats[DH + lane] * (1.f / N_NODES) - mu * mu;
    float inv = rsqrtf(var + BN_EPS);
    float h = gamma[lane] * (hpre[(size_t)g * DH + lane] - mu) * inv + beta[lane];
    float a = mb1[lane];
#pragma unroll
    for (int f = 0; f < DH; ++f) a += __shfl(h, f, 32) * mw1[f * DH + lane];
    float s = 1.f / (1.f + __expf(-a));
    float o0 = s * mw2[lane * 2 + 0];
    float o1 = s * mw2[lane * 2 + 1];
    for (int d = 16; d > 0; d >>= 1) {
        o0 += __shfl_xor(o0, d, 32);
        o1 += __shfl_xor(o1, d, 32);
    }
    if (lane == 0) {
        out[(size_t)g * 2 + 0] = o0 + mb2[0];
        out[(size_t)g * 2 + 1] = o1 + mb2[1];
    }
}

// ---------------- launch ----------------

extern "C" void kernel_launch(void* const* d_in, const int* in_sizes, int n_in,
                              void* d_out, int out_size, void* d_ws, size_t ws_size,
                              hipStream_t stream) {
    const float* x = (const float*)d_in[0];
    const int* edge_index = (const int*)d_in[1];
    const int* edge_type = (const int*)d_in[2];
    const float* w[3]  = {(const float*)d_in[3],  (const float*)d_in[9],  (const float*)d_in[15]};
    const float* aq[3] = {(const float*)d_in[4],  (const float*)d_in[10], (const float*)d_in[16]};
    const float* ak[3] = {(const float*)d_in[5],  (const float*)d_in[11], (const float*)d_in[17]};
    const float* bb[3] = {(const float*)d_in[6],  (const float*)d_in[12], (const float*)d_in[18]};
    const float* gm[3] = {(const float*)d_in[7],  (const float*)d_in[13], (const float*)d_in[19]};
    const float* be[3] = {(const float*)d_in[8],  (const float*)d_in[14], (const float*)d_in[20]};
    const float* mw1 = (const float*)d_in[21];
    const float* mb1 = (const float*)d_in[22];
    const float* mw2 = (const float*)d_in[23];
    const float* mb2 = (const float*)d_in[24];
    float* out = (float*)d_out;

    const int n = N_NODES, e = N_EDGES;
    char* ws = (char*)d_ws;
    auto alloc = [&](size_t bytes) {
        char* p = ws;
        ws += (bytes + 255) & ~(size_t)255;
        return p;
    };
    int* deg     = (int*)alloc((size_t)n * 4);
    int* off     = (int*)alloc((size_t)(n + 1) * 4);
    int* cursor  = (int*)alloc((size_t)n * 4);
    int* packed  = (int*)alloc((size_t)e * 4);
    float* y     = (float*)alloc((size_t)n * 2 * DH * 4);
    float* qv    = (float*)alloc((size_t)n * 2 * 4);
    float* kv    = (float*)alloc((size_t)n * 2 * 4);
    float* hpre  = (float*)alloc((size_t)n * DH * 4);
    float* stats = (float*)alloc(3 * 2 * DH * 4);

    hipMemsetAsync(deg, 0, (size_t)n * 4, stream);
    hipMemsetAsync(cursor, 0, (size_t)n * 4, stream);
    hipMemsetAsync(stats, 0, 3 * 2 * DH * 4, stream);

    const int* src = edge_index;
    const int* dst = edge_index + e;

    hist_kernel<<<(e + 255) / 256, 256, 0, stream>>>(dst, deg, e);
    scan_kernel<<<1, 1024, 0, stream>>>(deg, off, n);
    scatter_kernel<<<(e + 255) / 256, 256, 0, stream>>>(src, dst, edge_type, off, cursor, packed, e);

    // layer 0
    transform0_kernel<<<(n * 2 * 32 + 255) / 256, 256, 0, stream>>>(
        x, w[0], aq[0], ak[0], y, qv, kv, n);
    attn_kernel<<<2048, 256, 0, stream>>>(off, packed, y, qv, kv, bb[0], hpre, stats + 0 * 64, n);

    // layers 1, 2 (previous BN fused into transform)
    for (int li = 1; li < 3; ++li) {
        transform_h_kernel<<<(n * 2 * 32 + 255) / 256, 256, 0, stream>>>(
            hpre, stats + (li - 1) * 64, gm[li - 1], be[li - 1],
            w[li], aq[li], ak[li], y, qv, kv, n);
        attn_kernel<<<2048, 256, 0, stream>>>(off, packed, y, qv, kv, bb[li], hpre, stats + li * 64, n);
    }

    // final BN + MLP head
    mlp_kernel<<<(n * 32 + 255) / 256, 256, 0, stream>>>(
        hpre, stats + 2 * 64, gm[2], be[2], mw1, mb1, mw2, mb2, out, n);
}

// Round 3
// 755.237 us; speedup vs baseline: 1.3626x; 1.3626x over previous
//
#include <hip/hip_runtime.h>
#include <math.h>

#define N_NODES 100000
#define N_EDGES 1600000
#define DIN 128
#define DH 32
#define NEG_SLOPE 0.2f
#define BN_EPS 1e-5f
#define MT 64   // nodes per transform block

typedef __attribute__((ext_vector_type(8))) short short8;
typedef __attribute__((ext_vector_type(4))) float f32x4;

__device__ __forceinline__ unsigned short f2bf(float f) {
    unsigned int u = __float_as_uint(f);
    u = (u + 0x7FFFu + ((u >> 16) & 1u)) >> 16;
    return (unsigned short)u;
}
__device__ __forceinline__ float bf2f(unsigned short h) {
    return __uint_as_float((unsigned int)h << 16);
}

// ---------------- CSR build ----------------

__global__ void hist_kernel(const int* __restrict__ dst, int* __restrict__ deg, int e) {
    int i = blockIdx.x * blockDim.x + threadIdx.x;
    if (i < e) atomicAdd(&deg[dst[i]], 1);
}

__global__ void scan_kernel(const int* __restrict__ deg, int* __restrict__ off, int n) {
    __shared__ int part[1024];
    int t = threadIdx.x;
    int chunk = (n + 1023) >> 10;
    int lo = t * chunk, hi = min(lo + chunk, n);
    int s = 0;
    for (int i = lo; i < hi; ++i) s += deg[i];
    part[t] = s;
    __syncthreads();
    for (int d = 1; d < 1024; d <<= 1) {
        int v = (t >= d) ? part[t - d] : 0;
        __syncthreads();
        part[t] += v;
        __syncthreads();
    }
    int run = (t == 0) ? 0 : part[t - 1];
    for (int i = lo; i < hi; ++i) { off[i] = run; run += deg[i]; }
    if (t == 1023) off[n] = part[1023];
}

__global__ void scatter_kernel(const int* __restrict__ src, const int* __restrict__ dst,
                               const int* __restrict__ et, const int* __restrict__ off,
                               int* __restrict__ cursor, int* __restrict__ packed, int e) {
    int i = blockIdx.x * blockDim.x + threadIdx.x;
    if (i < e) {
        int d = dst[i];
        int pos = off[d] + atomicAdd(&cursor[d], 1);
        packed[pos] = src[i] | (et[i] << 30);
    }
}

// -------- weight conversion: Wt[col][k] = split-bf16 of w[r][k][c], col=r*32+c ----

__global__ void wconv_kernel(const float* __restrict__ w,
                             unsigned short* __restrict__ wt_hi,
                             unsigned short* __restrict__ wt_lo, int K) {
    int i = blockIdx.x * blockDim.x + threadIdx.x;
    if (i >= 64 * K) return;
    int col = i / K, k = i % K;
    int r = col >> 5, c = col & 31;
    float v = w[(r * K + k) * DH + c];
    unsigned short h = f2bf(v);
    wt_hi[i] = h;
    wt_lo[i] = f2bf(v - bf2f(h));
}

// ---------------- MFMA transform: y[node][64] = X[node][K] @ Wmat[K][64] ----------
// Split-bf16 (hi+lo) on both operands: acc = aH*bH + aH*bL + aL*bH  (~fp32 accuracy).
// Fuses previous layer's BN into staging (FUSE_BN) and q/k row-dots into epilogue.

template<int K, bool FUSE_BN>
__global__ __launch_bounds__(256) void transform_mfma_kernel(
    const float* __restrict__ xin, const float* __restrict__ stats,
    const float* __restrict__ gamma, const float* __restrict__ beta,
    const unsigned short* __restrict__ WtHi, const unsigned short* __restrict__ WtLo,
    const float* __restrict__ Qw, const float* __restrict__ Kw,
    float* __restrict__ y, float* __restrict__ qv, float* __restrict__ kv, int n) {
    constexpr int LDK = K + 8;          // +8 elems (16B) pad -> bank spread
    constexpr int KT = K / 32;
    __shared__ unsigned short xs_hi[MT * LDK];
    __shared__ unsigned short xs_lo[MT * LDK];
    __shared__ float scs[DH], shs[DH];
    int tid = threadIdx.x;
    int base = blockIdx.x * MT;

    if (FUSE_BN) {
        if (tid < DH) {
            float mu = stats[tid] * (1.f / N_NODES);
            float var = stats[DH + tid] * (1.f / N_NODES) - mu * mu;
            float inv = rsqrtf(var + BN_EPS);
            float sc = gamma[tid] * inv;
            scs[tid] = sc;
            shs[tid] = beta[tid] - mu * sc;
        }
        __syncthreads();
    }

    // stage X tile (fp32 -> hi/lo bf16) into LDS
    constexpr int CH = K / 4;
    for (int c = tid; c < MT * CH; c += 256) {
        int row = c / CH, c4 = c % CH;
        int node = base + row;
        float4 v = make_float4(0.f, 0.f, 0.f, 0.f);
        if (node < n) v = ((const float4*)(xin + (size_t)node * K))[c4];
        if (FUSE_BN) {
            int c0 = c4 * 4;
            v.x = v.x * scs[c0 + 0] + shs[c0 + 0];
            v.y = v.y * scs[c0 + 1] + shs[c0 + 1];
            v.z = v.z * scs[c0 + 2] + shs[c0 + 2];
            v.w = v.w * scs[c0 + 3] + shs[c0 + 3];
        }
        ushort4 hb = make_ushort4(f2bf(v.x), f2bf(v.y), f2bf(v.z), f2bf(v.w));
        ushort4 lb = make_ushort4(f2bf(v.x - bf2f(hb.x)), f2bf(v.y - bf2f(hb.y)),
                                  f2bf(v.z - bf2f(hb.z)), f2bf(v.w - bf2f(hb.w)));
        *(ushort4*)(&xs_hi[row * LDK + c4 * 4]) = hb;
        *(ushort4*)(&xs_lo[row * LDK + c4 * 4]) = lb;
    }
    __syncthreads();

    int lane = tid & 63;
    int wave = tid >> 6;                 // 4 waves x 16 rows
    int r16 = lane & 15, g = lane >> 4;  // frag coords
    int wrow = wave * 16;

    f32x4 acc[4];
#pragma unroll
    for (int nt = 0; nt < 4; ++nt) acc[nt] = f32x4{0.f, 0.f, 0.f, 0.f};

#pragma unroll
    for (int kt = 0; kt < KT; ++kt) {
        short8 a_hi = *(const short8*)(&xs_hi[(wrow + r16) * LDK + kt * 32 + g * 8]);
        short8 a_lo = *(const short8*)(&xs_lo[(wrow + r16) * LDK + kt * 32 + g * 8]);
#pragma unroll
        for (int nt = 0; nt < 4; ++nt) {
            const size_t bo = (size_t)(nt * 16 + r16) * K + kt * 32 + g * 8;
            short8 b_hi = *(const short8*)(WtHi + bo);
            short8 b_lo = *(const short8*)(WtLo + bo);
            acc[nt] = __builtin_amdgcn_mfma_f32_16x16x32_bf16(a_hi, b_hi, acc[nt], 0, 0, 0);
            acc[nt] = __builtin_amdgcn_mfma_f32_16x16x32_bf16(a_hi, b_lo, acc[nt], 0, 0, 0);
            acc[nt] = __builtin_amdgcn_mfma_f32_16x16x32_bf16(a_lo, b_hi, acc[nt], 0, 0, 0);
        }
    }

    // epilogue: y stores + fused q/k row-dots
    float qp[2][4] = {{0.f, 0.f, 0.f, 0.f}, {0.f, 0.f, 0.f, 0.f}};
    float kp[2][4] = {{0.f, 0.f, 0.f, 0.f}, {0.f, 0.f, 0.f, 0.f}};
#pragma unroll
    for (int nt = 0; nt < 4; ++nt) {
        int col = nt * 16 + r16;
        int rr = col >> 5, cc = col & 31;
        float qw = Qw[rr * DH + cc], kw = Kw[rr * DH + cc];
#pragma unroll
        for (int j = 0; j < 4; ++j) {
            float v = acc[nt][j];
            qp[rr][j] += v * qw;
            kp[rr][j] += v * kw;
            int node = base + wrow + g * 4 + j;
            if (node < n) y[(size_t)node * 64 + col] = v;
        }
    }
#pragma unroll
    for (int j = 0; j < 4; ++j) {
#pragma unroll
        for (int rr = 0; rr < 2; ++rr) {
            float q = qp[rr][j], k = kp[rr][j];
            for (int d = 8; d; d >>= 1) {
                q += __shfl_xor(q, d, 16);
                k += __shfl_xor(k, d, 16);
            }
            if (r16 == 0) {
                int node = base + wrow + g * 4 + j;
                if (node < n) {
                    qv[node * 2 + rr] = q;
                    kv[node * 2 + rr] = k;
                }
            }
        }
    }
}

// ---------------- fused attention + aggregate + relu + BN stats ----------------
// Softmax max-pass dropped: exp(e-8) is shift-equivalent and safely in fp32 range.

__global__ __launch_bounds__(256) void attn_kernel(
    const int* __restrict__ off, const int* __restrict__ packed,
    const float* __restrict__ y, const float* __restrict__ qv, const float* __restrict__ kv,
    const float* __restrict__ bias, float* __restrict__ ebuf, float* __restrict__ hpre,
    float* __restrict__ stats, int n) {
    __shared__ float ssum[DH], ssq[DH];
    if (threadIdx.x < DH) { ssum[threadIdx.x] = 0.f; ssq[threadIdx.x] = 0.f; }
    __syncthreads();
    int lane = threadIdx.x & 31;
    int sub = threadIdx.x >> 5;
    int spb = blockDim.x >> 5;
    float rsum = 0.f, rsq = 0.f;
    for (int node = blockIdx.x * spb + sub; node < n; node += gridDim.x * spb) {
        int lo = off[node], hi = off[node + 1];
        float q0 = qv[node * 2], q1 = qv[node * 2 + 1];
        // pass A: unnormalized weights, cached in ebuf
        float sum = 0.f;
        for (int i = lo + lane; i < hi; i += 32) {
            int p = packed[i];
            int s = p & 0x3FFFFFFF, r = p >> 30;
            float e = (r ? q1 : q0) + kv[s * 2 + r];
            e = e > 0.f ? e : NEG_SLOPE * e;
            float w = __expf(e - 8.f);
            ebuf[i] = w;
            sum += w;
        }
        for (int d = 16; d; d >>= 1) sum += __shfl_xor(sum, d, 32);
        asm volatile("s_waitcnt vmcnt(0)" ::: "memory");  // ebuf visible to all lanes
        float inv = 1.f / (sum + 1e-16f);
        // pass B: weighted aggregation, lane = feature, 2-way unrolled
        float acc0 = 0.f, acc1 = 0.f;
        int i = lo;
        for (; i + 2 <= hi; i += 2) {
            int p0 = packed[i], p1 = packed[i + 1];
            float w0 = ebuf[i], w1 = ebuf[i + 1];
            acc0 += w0 * y[(size_t)((p0 & 0x3FFFFFFF) * 2 + (p0 >> 30)) * DH + lane];
            acc1 += w1 * y[(size_t)((p1 & 0x3FFFFFFF) * 2 + (p1 >> 30)) * DH + lane];
        }
        if (i < hi) {
            int p0 = packed[i];
            acc0 += ebuf[i] * y[(size_t)((p0 & 0x3FFFFFFF) * 2 + (p0 >> 30)) * DH + lane];
        }
        float h = fmaxf((acc0 + acc1) * inv + bias[lane], 0.f);
        hpre[(size_t)node * DH + lane] = h;
        rsum += h;
        rsq += h * h;
    }
    atomicAdd(&ssum[lane], rsum);
    atomicAdd(&ssq[lane], rsq);
    __syncthreads();
    if (threadIdx.x < DH) {
        atomicAdd(&stats[threadIdx.x], ssum[threadIdx.x]);
        atomicAdd(&stats[DH + threadIdx.x], ssq[threadIdx.x]);
    }
}

// ---------------- final BN + MLP head ----------------

__global__ __launch_bounds__(256) void mlp_kernel(
    const float* __restrict__ hpre, const float* __restrict__ stats,
    const float* __restrict__ gamma, const float* __restrict__ beta,
    const float* __restrict__ mw1, const float* __restrict__ mb1,
    const float* __restrict__ mw2, const float* __restrict__ mb2,
    float* __restrict__ out, int n) {
    int g = (blockIdx.x * blockDim.x + threadIdx.x) >> 5;
    int lane = threadIdx.x & 31;
    if (g >= n) return;
    float mu = stats[lane] * (1.f / N_NODES);
    float var = stats[DH + lane] * (1.f / N_NODES) - mu * mu;
    float inv = rsqrtf(var + BN_EPS);
    float h = gamma[lane] * (hpre[(size_t)g * DH + lane] - mu) * inv + beta[lane];
    float a = mb1[lane];
#pragma unroll
    for (int f = 0; f < DH; ++f) a += __shfl(h, f, 32) * mw1[f * DH + lane];
    float s = 1.f / (1.f + __expf(-a));
    float o0 = s * mw2[lane * 2 + 0];
    float o1 = s * mw2[lane * 2 + 1];
    for (int d = 16; d; d >>= 1) {
        o0 += __shfl_xor(o0, d, 32);
        o1 += __shfl_xor(o1, d, 32);
    }
    if (lane == 0) {
        out[(size_t)g * 2 + 0] = o0 + mb2[0];
        out[(size_t)g * 2 + 1] = o1 + mb2[1];
    }
}

// ---------------- launch ----------------

extern "C" void kernel_launch(void* const* d_in, const int* in_sizes, int n_in,
                              void* d_out, int out_size, void* d_ws, size_t ws_size,
                              hipStream_t stream) {
    const float* x = (const float*)d_in[0];
    const int* edge_index = (const int*)d_in[1];
    const int* edge_type = (const int*)d_in[2];
    const float* w[3]  = {(const float*)d_in[3],  (const float*)d_in[9],  (const float*)d_in[15]};
    const float* aq[3] = {(const float*)d_in[4],  (const float*)d_in[10], (const float*)d_in[16]};
    const float* ak[3] = {(const float*)d_in[5],  (const float*)d_in[11], (const float*)d_in[17]};
    const float* bb[3] = {(const float*)d_in[6],  (const float*)d_in[12], (const float*)d_in[18]};
    const float* gm[3] = {(const float*)d_in[7],  (const float*)d_in[13], (const float*)d_in[19]};
    const float* be[3] = {(const float*)d_in[8],  (const float*)d_in[14], (const float*)d_in[20]};
    const float* mw1 = (const float*)d_in[21];
    const float* mb1 = (const float*)d_in[22];
    const float* mw2 = (const float*)d_in[23];
    const float* mb2 = (const float*)d_in[24];
    float* out = (float*)d_out;

    const int n = N_NODES, e = N_EDGES;
    char* ws = (char*)d_ws;
    auto alloc = [&](size_t bytes) {
        char* p = ws;
        ws += (bytes + 255) & ~(size_t)255;
        return p;
    };
    int* deg     = (int*)alloc((size_t)n * 4);
    int* off     = (int*)alloc((size_t)(n + 1) * 4);
    int* cursor  = (int*)alloc((size_t)n * 4);
    int* packed  = (int*)alloc((size_t)e * 4);
    float* y     = (float*)alloc((size_t)n * 2 * DH * 4);
    float* qv    = (float*)alloc((size_t)n * 2 * 4);
    float* kv    = (float*)alloc((size_t)n * 2 * 4);
    float* hpre  = (float*)alloc((size_t)n * DH * 4);
    float* ebuf  = (float*)alloc((size_t)e * 4);
    float* stats = (float*)alloc(3 * 2 * DH * 4);
    unsigned short* wt0h = (unsigned short*)alloc((size_t)64 * DIN * 2);
    unsigned short* wt0l = (unsigned short*)alloc((size_t)64 * DIN * 2);
    unsigned short* wt1h = (unsigned short*)alloc((size_t)64 * DH * 2);
    unsigned short* wt1l = (unsigned short*)alloc((size_t)64 * DH * 2);
    unsigned short* wt2h = (unsigned short*)alloc((size_t)64 * DH * 2);
    unsigned short* wt2l = (unsigned short*)alloc((size_t)64 * DH * 2);

    hipMemsetAsync(deg, 0, (size_t)n * 4, stream);
    hipMemsetAsync(cursor, 0, (size_t)n * 4, stream);
    hipMemsetAsync(stats, 0, 3 * 2 * DH * 4, stream);

    const int* src = edge_index;
    const int* dst = edge_index + e;

    wconv_kernel<<<(64 * DIN + 255) / 256, 256, 0, stream>>>(w[0], wt0h, wt0l, DIN);
    wconv_kernel<<<(64 * DH + 255) / 256, 256, 0, stream>>>(w[1], wt1h, wt1l, DH);
    wconv_kernel<<<(64 * DH + 255) / 256, 256, 0, stream>>>(w[2], wt2h, wt2l, DH);

    hist_kernel<<<(e + 255) / 256, 256, 0, stream>>>(dst, deg, e);
    scan_kernel<<<1, 1024, 0, stream>>>(deg, off, n);
    scatter_kernel<<<(e + 255) / 256, 256, 0, stream>>>(src, dst, edge_type, off, cursor, packed, e);

    int tblocks = (n + MT - 1) / MT;

    // layer 0
    transform_mfma_kernel<DIN, false><<<tblocks, 256, 0, stream>>>(
        x, nullptr, nullptr, nullptr, wt0h, wt0l, aq[0], ak[0], y, qv, kv, n);
    attn_kernel<<<2048, 256, 0, stream>>>(off, packed, y, qv, kv, bb[0], ebuf, hpre, stats + 0 * 64, n);

    // layer 1
    transform_mfma_kernel<DH, true><<<tblocks, 256, 0, stream>>>(
        hpre, stats + 0 * 64, gm[0], be[0], wt1h, wt1l, aq[1], ak[1], y, qv, kv, n);
    attn_kernel<<<2048, 256, 0, stream>>>(off, packed, y, qv, kv, bb[1], ebuf, hpre, stats + 1 * 64, n);

    // layer 2
    transform_mfma_kernel<DH, true><<<tblocks, 256, 0, stream>>>(
        hpre, stats + 1 * 64, gm[1], be[1], wt2h, wt2l, aq[2], ak[2], y, qv, kv, n);
    attn_kernel<<<2048, 256, 0, stream>>>(off, packed, y, qv, kv, bb[2], ebuf, hpre, stats + 2 * 64, n);

    // final BN + MLP head
    mlp_kernel<<<((size_t)n * 32 + 255) / 256, 256, 0, stream>>>(
        hpre, stats + 2 * 64, gm[2], be[2], mw1, mb1, mw2, mb2, out, n);
}

// Round 4
// 603.811 us; speedup vs baseline: 1.7043x; 1.2508x over previous
//
#include <hip/hip_runtime.h>
#include <math.h>

#define N_NODES 100000
#define N_EDGES 1600000
#define DIN 128
#define DH 32
#define NEG_SLOPE 0.2f
#define BN_EPS 1e-5f
#define MT 64        // nodes per transform block
#define SCHUNK 512   // scan chunk

typedef __attribute__((ext_vector_type(8))) short short8;
typedef __attribute__((ext_vector_type(4))) float f32x4;

__device__ __forceinline__ unsigned short f2bf(float f) {
    unsigned int u = __float_as_uint(f);
    u = (u + 0x7FFFu + ((u >> 16) & 1u)) >> 16;
    return (unsigned short)u;
}
__device__ __forceinline__ float bf2f(unsigned short h) {
    return __uint_as_float((unsigned int)h << 16);
}

// ---------------- CSR build ----------------

__global__ void hist_kernel(const int* __restrict__ dst, int* __restrict__ deg, int e) {
    int i = blockIdx.x * blockDim.x + threadIdx.x;
    if (i < e) atomicAdd(&deg[dst[i]], 1);
}

// two-level scan: (1) per-block chunk sums
__global__ __launch_bounds__(256) void scan_part_kernel(
    const int* __restrict__ deg, int* __restrict__ partials, int n) {
    __shared__ int sdata[256];
    int b = blockIdx.x, t = threadIdx.x;
    int i0 = b * SCHUNK + t;
    int s = 0;
    if (i0 < n) s += deg[i0];
    if (i0 + 256 < n && t + 256 < SCHUNK) s += deg[i0 + 256];
    sdata[t] = s;
    __syncthreads();
    for (int d = 128; d; d >>= 1) {
        if (t < d) sdata[t] += sdata[t + d];
        __syncthreads();
    }
    if (t == 0) partials[b] = sdata[0];
}

// (2) single-block exclusive scan of partials (nb <= 1024)
__global__ __launch_bounds__(1024) void scan_top_kernel(int* __restrict__ partials, int nb) {
    __shared__ int sdata[1024];
    int t = threadIdx.x;
    sdata[t] = (t < nb) ? partials[t] : 0;
    __syncthreads();
    for (int d = 1; d < 1024; d <<= 1) {
        int v = (t >= d) ? sdata[t - d] : 0;
        __syncthreads();
        sdata[t] += v;
        __syncthreads();
    }
    if (t < nb) partials[t] = (t == 0) ? 0 : sdata[t - 1];
}

// (3) per-chunk exclusive scan + chunk base
__global__ __launch_bounds__(SCHUNK) void scan_final_kernel(
    const int* __restrict__ deg, const int* __restrict__ partials,
    int* __restrict__ off, int n, int e) {
    __shared__ int sdata[SCHUNK];
    int b = blockIdx.x, t = threadIdx.x;
    int i = b * SCHUNK + t;
    sdata[t] = (i < n) ? deg[i] : 0;
    __syncthreads();
    for (int d = 1; d < SCHUNK; d <<= 1) {
        int v = (t >= d) ? sdata[t - d] : 0;
        __syncthreads();
        sdata[t] += v;
        __syncthreads();
    }
    int excl = (t == 0) ? 0 : sdata[t - 1];
    if (i < n) off[i] = partials[b] + excl;
    if (b == 0 && t == 0) off[n] = e;
}

__global__ void scatter_kernel(const int* __restrict__ src, const int* __restrict__ dst,
                               const int* __restrict__ et, const int* __restrict__ off,
                               int* __restrict__ cursor, int* __restrict__ packed, int e) {
    int i = blockIdx.x * blockDim.x + threadIdx.x;
    if (i < e) {
        int d = dst[i];
        int pos = off[d] + atomicAdd(&cursor[d], 1);
        packed[pos] = src[i] | (et[i] << 30);
    }
}

// -------- weight conversion: Wt[col][k] = split-bf16 of w[r][k][c], col=r*32+c ----

__global__ void wconv_kernel(const float* __restrict__ w,
                             unsigned short* __restrict__ wt_hi,
                             unsigned short* __restrict__ wt_lo, int K) {
    int i = blockIdx.x * blockDim.x + threadIdx.x;
    if (i >= 64 * K) return;
    int col = i / K, k = i % K;
    int r = col >> 5, c = col & 31;
    float v = w[(r * K + k) * DH + c];
    unsigned short h = f2bf(v);
    wt_hi[i] = h;
    wt_lo[i] = f2bf(v - bf2f(h));
}

// ---------------- MFMA transform: y[node][64] = X[node][K] @ Wmat[K][64] ----------
// Split-bf16 (hi+lo) on both operands: acc = aH*bH + aH*bL + aL*bH  (~fp32 accuracy).
// Fuses previous layer's BN into staging (FUSE_BN) and q/k row-dots into epilogue.

template<int K, bool FUSE_BN>
__global__ __launch_bounds__(256) void transform_mfma_kernel(
    const float* __restrict__ xin, const float* __restrict__ stats,
    const float* __restrict__ gamma, const float* __restrict__ beta,
    const unsigned short* __restrict__ WtHi, const unsigned short* __restrict__ WtLo,
    const float* __restrict__ Qw, const float* __restrict__ Kw,
    float* __restrict__ y, float* __restrict__ qv, float* __restrict__ kv, int n) {
    constexpr int LDK = K + 8;          // +8 elems (16B) pad -> bank spread
    constexpr int KT = K / 32;
    __shared__ unsigned short xs_hi[MT * LDK];
    __shared__ unsigned short xs_lo[MT * LDK];
    __shared__ float scs[DH], shs[DH];
    int tid = threadIdx.x;
    int base = blockIdx.x * MT;

    if (FUSE_BN) {
        if (tid < DH) {
            float mu = stats[tid] * (1.f / N_NODES);
            float var = stats[DH + tid] * (1.f / N_NODES) - mu * mu;
            float inv = rsqrtf(var + BN_EPS);
            float sc = gamma[tid] * inv;
            scs[tid] = sc;
            shs[tid] = beta[tid] - mu * sc;
        }
        __syncthreads();
    }

    // stage X tile (fp32 -> hi/lo bf16) into LDS
    constexpr int CH = K / 4;
    for (int c = tid; c < MT * CH; c += 256) {
        int row = c / CH, c4 = c % CH;
        int node = base + row;
        float4 v = make_float4(0.f, 0.f, 0.f, 0.f);
        if (node < n) v = ((const float4*)(xin + (size_t)node * K))[c4];
        if (FUSE_BN) {
            int c0 = c4 * 4;
            v.x = v.x * scs[c0 + 0] + shs[c0 + 0];
            v.y = v.y * scs[c0 + 1] + shs[c0 + 1];
            v.z = v.z * scs[c0 + 2] + shs[c0 + 2];
            v.w = v.w * scs[c0 + 3] + shs[c0 + 3];
        }
        ushort4 hb = make_ushort4(f2bf(v.x), f2bf(v.y), f2bf(v.z), f2bf(v.w));
        ushort4 lb = make_ushort4(f2bf(v.x - bf2f(hb.x)), f2bf(v.y - bf2f(hb.y)),
                                  f2bf(v.z - bf2f(hb.z)), f2bf(v.w - bf2f(hb.w)));
        *(ushort4*)(&xs_hi[row * LDK + c4 * 4]) = hb;
        *(ushort4*)(&xs_lo[row * LDK + c4 * 4]) = lb;
    }
    __syncthreads();

    int lane = tid & 63;
    int wave = tid >> 6;                 // 4 waves x 16 rows
    int r16 = lane & 15, g = lane >> 4;  // frag coords
    int wrow = wave * 16;

    f32x4 acc[4];
#pragma unroll
    for (int nt = 0; nt < 4; ++nt) acc[nt] = f32x4{0.f, 0.f, 0.f, 0.f};

#pragma unroll
    for (int kt = 0; kt < KT; ++kt) {
        short8 a_hi = *(const short8*)(&xs_hi[(wrow + r16) * LDK + kt * 32 + g * 8]);
        short8 a_lo = *(const short8*)(&xs_lo[(wrow + r16) * LDK + kt * 32 + g * 8]);
#pragma unroll
        for (int nt = 0; nt < 4; ++nt) {
            const size_t bo = (size_t)(nt * 16 + r16) * K + kt * 32 + g * 8;
            short8 b_hi = *(const short8*)(WtHi + bo);
            short8 b_lo = *(const short8*)(WtLo + bo);
            acc[nt] = __builtin_amdgcn_mfma_f32_16x16x32_bf16(a_hi, b_hi, acc[nt], 0, 0, 0);
            acc[nt] = __builtin_amdgcn_mfma_f32_16x16x32_bf16(a_hi, b_lo, acc[nt], 0, 0, 0);
            acc[nt] = __builtin_amdgcn_mfma_f32_16x16x32_bf16(a_lo, b_hi, acc[nt], 0, 0, 0);
        }
    }

    // epilogue: y stores + fused q/k row-dots
    float qp[2][4] = {{0.f, 0.f, 0.f, 0.f}, {0.f, 0.f, 0.f, 0.f}};
    float kp[2][4] = {{0.f, 0.f, 0.f, 0.f}, {0.f, 0.f, 0.f, 0.f}};
#pragma unroll
    for (int nt = 0; nt < 4; ++nt) {
        int col = nt * 16 + r16;
        int rr = col >> 5, cc = col & 31;
        float qw = Qw[rr * DH + cc], kw = Kw[rr * DH + cc];
#pragma unroll
        for (int j = 0; j < 4; ++j) {
            float v = acc[nt][j];
            qp[rr][j] += v * qw;
            kp[rr][j] += v * kw;
            int node = base + wrow + g * 4 + j;
            if (node < n) y[(size_t)node * 64 + col] = v;
        }
    }
#pragma unroll
    for (int j = 0; j < 4; ++j) {
#pragma unroll
        for (int rr = 0; rr < 2; ++rr) {
            float q = qp[rr][j], k = kp[rr][j];
            for (int d = 8; d; d >>= 1) {
                q += __shfl_xor(q, d, 16);
                k += __shfl_xor(k, d, 16);
            }
            if (r16 == 0) {
                int node = base + wrow + g * 4 + j;
                if (node < n) {
                    qv[node * 2 + rr] = q;
                    kv[node * 2 + rr] = k;
                }
            }
        }
    }
}

// ---------------- fused attention + aggregate + relu + BN stats ----------------
// Softmax max-pass dropped: exp(e-8) is shift-equivalent and safely in fp32 range.

__global__ __launch_bounds__(256) void attn_kernel(
    const int* __restrict__ off, const int* __restrict__ packed,
    const float* __restrict__ y, const float* __restrict__ qv, const float* __restrict__ kv,
    const float* __restrict__ bias, float* __restrict__ ebuf, float* __restrict__ hpre,
    float* __restrict__ stats, int n) {
    __shared__ float ssum[DH], ssq[DH];
    if (threadIdx.x < DH) { ssum[threadIdx.x] = 0.f; ssq[threadIdx.x] = 0.f; }
    __syncthreads();
    int lane = threadIdx.x & 31;
    int sub = threadIdx.x >> 5;
    int spb = blockDim.x >> 5;
    float rsum = 0.f, rsq = 0.f;
    for (int node = blockIdx.x * spb + sub; node < n; node += gridDim.x * spb) {
        int lo = off[node], hi = off[node + 1];
        float q0 = qv[node * 2], q1 = qv[node * 2 + 1];
        // pass A: unnormalized weights, cached in ebuf
        float sum = 0.f;
        for (int i = lo + lane; i < hi; i += 32) {
            int p = packed[i];
            int s = p & 0x3FFFFFFF, r = p >> 30;
            float e = (r ? q1 : q0) + kv[s * 2 + r];
            e = e > 0.f ? e : NEG_SLOPE * e;
            float w = __expf(e - 8.f);
            ebuf[i] = w;
            sum += w;
        }
        for (int d = 16; d; d >>= 1) sum += __shfl_xor(sum, d, 32);
        asm volatile("s_waitcnt vmcnt(0)" ::: "memory");  // ebuf visible to all lanes
        float inv = 1.f / (sum + 1e-16f);
        // pass B: weighted aggregation, lane = feature, 2-way unrolled
        float acc0 = 0.f, acc1 = 0.f;
        int i = lo;
        for (; i + 2 <= hi; i += 2) {
            int p0 = packed[i], p1 = packed[i + 1];
            float w0 = ebuf[i], w1 = ebuf[i + 1];
            acc0 += w0 * y[(size_t)((p0 & 0x3FFFFFFF) * 2 + (p0 >> 30)) * DH + lane];
            acc1 += w1 * y[(size_t)((p1 & 0x3FFFFFFF) * 2 + (p1 >> 30)) * DH + lane];
        }
        if (i < hi) {
            int p0 = packed[i];
            acc0 += ebuf[i] * y[(size_t)((p0 & 0x3FFFFFFF) * 2 + (p0 >> 30)) * DH + lane];
        }
        float h = fmaxf((acc0 + acc1) * inv + bias[lane], 0.f);
        hpre[(size_t)node * DH + lane] = h;
        rsum += h;
        rsq += h * h;
    }
    atomicAdd(&ssum[lane], rsum);
    atomicAdd(&ssq[lane], rsq);
    __syncthreads();
    if (threadIdx.x < DH) {
        atomicAdd(&stats[threadIdx.x], ssum[threadIdx.x]);
        atomicAdd(&stats[DH + threadIdx.x], ssq[threadIdx.x]);
    }
}

// ---------------- final BN + MLP head ----------------

__global__ __launch_bounds__(256) void mlp_kernel(
    const float* __restrict__ hpre, const float* __restrict__ stats,
    const float* __restrict__ gamma, const float* __restrict__ beta,
    const float* __restrict__ mw1, const float* __restrict__ mb1,
    const float* __restrict__ mw2, const float* __restrict__ mb2,
    float* __restrict__ out, int n) {
    int g = (blockIdx.x * blockDim.x + threadIdx.x) >> 5;
    int lane = threadIdx.x & 31;
    if (g >= n) return;
    float mu = stats[lane] * (1.f / N_NODES);
    float var = stats[DH + lane] * (1.f / N_NODES) - mu * mu;
    float inv = rsqrtf(var + BN_EPS);
    float h = gamma[lane] * (hpre[(size_t)g * DH + lane] - mu) * inv + beta[lane];
    float a = mb1[lane];
#pragma unroll
    for (int f = 0; f < DH; ++f) a += __shfl(h, f, 32) * mw1[f * DH + lane];
    float s = 1.f / (1.f + __expf(-a));
    float o0 = s * mw2[lane * 2 + 0];
    float o1 = s * mw2[lane * 2 + 1];
    for (int d = 16; d; d >>= 1) {
        o0 += __shfl_xor(o0, d, 32);
        o1 += __shfl_xor(o1, d, 32);
    }
    if (lane == 0) {
        out[(size_t)g * 2 + 0] = o0 + mb2[0];
        out[(size_t)g * 2 + 1] = o1 + mb2[1];
    }
}

// ---------------- launch ----------------

extern "C" void kernel_launch(void* const* d_in, const int* in_sizes, int n_in,
                              void* d_out, int out_size, void* d_ws, size_t ws_size,
                              hipStream_t stream) {
    const float* x = (const float*)d_in[0];
    const int* edge_index = (const int*)d_in[1];
    const int* edge_type = (const int*)d_in[2];
    const float* w[3]  = {(const float*)d_in[3],  (const float*)d_in[9],  (const float*)d_in[15]};
    const float* aq[3] = {(const float*)d_in[4],  (const float*)d_in[10], (const float*)d_in[16]};
    const float* ak[3] = {(const float*)d_in[5],  (const float*)d_in[11], (const float*)d_in[17]};
    const float* bb[3] = {(const float*)d_in[6],  (const float*)d_in[12], (const float*)d_in[18]};
    const float* gm[3] = {(const float*)d_in[7],  (const float*)d_in[13], (const float*)d_in[19]};
    const float* be[3] = {(const float*)d_in[8],  (const float*)d_in[14], (const float*)d_in[20]};
    const float* mw1 = (const float*)d_in[21];
    const float* mb1 = (const float*)d_in[22];
    const float* mw2 = (const float*)d_in[23];
    const float* mb2 = (const float*)d_in[24];
    float* out = (float*)d_out;

    const int n = N_NODES, e = N_EDGES;
    char* ws = (char*)d_ws;
    auto alloc = [&](size_t bytes) {
        char* p = ws;
        ws += (bytes + 255) & ~(size_t)255;
        return p;
    };
    int* deg      = (int*)alloc((size_t)n * 4);
    int* off      = (int*)alloc((size_t)(n + 1) * 4);
    int* cursor   = (int*)alloc((size_t)n * 4);
    int* partials = (int*)alloc((size_t)1024 * 4);
    int* packed   = (int*)alloc((size_t)e * 4);
    float* y      = (float*)alloc((size_t)n * 2 * DH * 4);
    float* qv     = (float*)alloc((size_t)n * 2 * 4);
    float* kv     = (float*)alloc((size_t)n * 2 * 4);
    float* hpre   = (float*)alloc((size_t)n * DH * 4);
    float* ebuf   = (float*)alloc((size_t)e * 4);
    float* stats  = (float*)alloc(3 * 2 * DH * 4);
    unsigned short* wt0h = (unsigned short*)alloc((size_t)64 * DIN * 2);
    unsigned short* wt0l = (unsigned short*)alloc((size_t)64 * DIN * 2);
    unsigned short* wt1h = (unsigned short*)alloc((size_t)64 * DH * 2);
    unsigned short* wt1l = (unsigned short*)alloc((size_t)64 * DH * 2);
    unsigned short* wt2h = (unsigned short*)alloc((size_t)64 * DH * 2);
    unsigned short* wt2l = (unsigned short*)alloc((size_t)64 * DH * 2);

    hipMemsetAsync(deg, 0, (size_t)n * 4, stream);
    hipMemsetAsync(cursor, 0, (size_t)n * 4, stream);
    hipMemsetAsync(stats, 0, 3 * 2 * DH * 4, stream);

    const int* src = edge_index;
    const int* dst = edge_index + e;

    wconv_kernel<<<(64 * DIN + 255) / 256, 256, 0, stream>>>(w[0], wt0h, wt0l, DIN);
    wconv_kernel<<<(64 * DH + 255) / 256, 256, 0, stream>>>(w[1], wt1h, wt1l, DH);
    wconv_kernel<<<(64 * DH + 255) / 256, 256, 0, stream>>>(w[2], wt2h, wt2l, DH);

    hist_kernel<<<(e + 255) / 256, 256, 0, stream>>>(dst, deg, e);
    int nb = (n + SCHUNK - 1) / SCHUNK;
    scan_part_kernel<<<nb, 256, 0, stream>>>(deg, partials, n);
    scan_top_kernel<<<1, 1024, 0, stream>>>(partials, nb);
    scan_final_kernel<<<nb, SCHUNK, 0, stream>>>(deg, partials, off, n, e);
    scatter_kernel<<<(e + 255) / 256, 256, 0, stream>>>(src, dst, edge_type, off, cursor, packed, e);

    int tblocks = (n + MT - 1) / MT;

    // layer 0
    transform_mfma_kernel<DIN, false><<<tblocks, 256, 0, stream>>>(
        x, nullptr, nullptr, nullptr, wt0h, wt0l, aq[0], ak[0], y, qv, kv, n);
    attn_kernel<<<2048, 256, 0, stream>>>(off, packed, y, qv, kv, bb[0], ebuf, hpre, stats + 0 * 64, n);

    // layer 1
    transform_mfma_kernel<DH, true><<<tblocks, 256, 0, stream>>>(
        hpre, stats + 0 * 64, gm[0], be[0], wt1h, wt1l, aq[1], ak[1], y, qv, kv, n);
    attn_kernel<<<2048, 256, 0, stream>>>(off, packed, y, qv, kv, bb[1], ebuf, hpre, stats + 1 * 64, n);

    // layer 2
    transform_mfma_kernel<DH, true><<<tblocks, 256, 0, stream>>>(
        hpre, stats + 1 * 64, gm[1], be[1], wt2h, wt2l, aq[2], ak[2], y, qv, kv, n);
    attn_kernel<<<2048, 256, 0, stream>>>(off, packed, y, qv, kv, bb[2], ebuf, hpre, stats + 2 * 64, n);

    // final BN + MLP head
    mlp_kernel<<<((size_t)n * 32 + 255) / 256, 256, 0, stream>>>(
        hpre, stats + 2 * 64, gm[2], be[2], mw1, mb1, mw2, mb2, out, n);
}